// Round 1
// baseline (287.041 us; speedup 1.0000x reference)
//
#include <hip/hip_runtime.h>
#include <cstdint>
#include <cstddef>

// MHA: B=2, S=2048, D=1024, H=16, DK=DV=64, causal, scale=1/8 on scores.
// Pipeline: (1) weights -> bf16 W^T, (2) Q/K/V projections (bf16 MFMA GEMM),
// (3) causal flash attention, (4) output GEMM -> fp32.

typedef __bf16 bf16x8 __attribute__((ext_vector_type(8)));
typedef __bf16 bf16x4 __attribute__((ext_vector_type(4)));
typedef float f32x4 __attribute__((ext_vector_type(4)));
typedef unsigned int u32x4 __attribute__((ext_vector_type(4)));

#define MFMA __builtin_amdgcn_mfma_f32_16x16x32_bf16

static __device__ __forceinline__ __bf16 f2b(float f) { return (__bf16)f; }

// ---------------------------------------------------------------------------
// Weight transpose+convert: O[n][k] = (bf16) W[k][n], each 1024x1024.
// grid (32,32,4), block 256. z selects Wq/Wk/Wv/Wo.
// ---------------------------------------------------------------------------
__global__ __launch_bounds__(256) void wtrans_kernel(
    const float* __restrict__ w0, const float* __restrict__ w1,
    const float* __restrict__ w2, const float* __restrict__ w3,
    __bf16* __restrict__ outT)
{
  const int z = blockIdx.z;
  const float* W = (z == 0) ? w0 : (z == 1) ? w1 : (z == 2) ? w2 : w3;
  __bf16* O = outT + (size_t)z * 1048576;
  __shared__ float t[32][33];
  const int tx = threadIdx.x & 31, ty = threadIdx.x >> 5;  // ty 0..7
  const int kb = blockIdx.y * 32, nb = blockIdx.x * 32;
#pragma unroll
  for (int i = 0; i < 4; i++)
    t[ty + i * 8][tx] = W[(size_t)(kb + ty + i * 8) * 1024 + nb + tx];
  __syncthreads();
#pragma unroll
  for (int i = 0; i < 4; i++)
    O[(size_t)(nb + ty + i * 8) * 1024 + kb + tx] = f2b(t[tx][ty + i * 8]);
}

// ---------------------------------------------------------------------------
// Projection GEMM: C = A(fp32 [4096,1024]) * W(bf16 W^T layout [1024n][1024k])
// Output bf16 scattered to [B=2, H=16, S=2048, 64] head-major.
// grid (256, 3): x = tile (mt*8+nt), y selects Q/K/V. block 256 (4 waves).
// Tile 128x128, BK=32, wave grid 2x2 (each wave 64x64 = 4x4 MFMA tiles).
// ---------------------------------------------------------------------------
__global__ __launch_bounds__(256) void gemm_proj_kernel(
    const float* __restrict__ A0, const float* __restrict__ A1,
    const float* __restrict__ A2, const __bf16* __restrict__ WT,
    __bf16* __restrict__ C0, __bf16* __restrict__ C1, __bf16* __restrict__ C2)
{
  const int z = blockIdx.y;
  const float* A = (z == 0) ? A0 : (z == 1) ? A1 : A2;
  const __bf16* W = WT + (size_t)z * 1048576;
  __bf16* C = (z == 0) ? C0 : (z == 1) ? C1 : C2;

  const int mt = blockIdx.x >> 3, nt = blockIdx.x & 7;
  const int mbase = mt * 128, nbase = nt * 128;

  __shared__ __align__(16) __bf16 As[128][40];
  __shared__ __align__(16) __bf16 Bs[128][40];

  const int tid = threadIdx.x;
  const int wid = tid >> 6, lane = tid & 63;
  const int wr = wid >> 1, wc = wid & 1;
  const int lr = lane & 15, kg = lane >> 4;

  f32x4 acc[4][4] = {};

  const int arow = tid >> 3, ac0 = (tid & 7) * 4;  // A staging: 32 rows/pass

  for (int kb = 0; kb < 32; ++kb) {
    const int k0 = kb * 32;
    // stage A: fp32 -> bf16, rows contiguous in k
#pragma unroll
    for (int p = 0; p < 4; ++p) {
      const int r = arow + p * 32;
      f32x4 av = *(const f32x4*)&A[(size_t)(mbase + r) * 1024 + k0 + ac0];
      bf16x4 cv = {f2b(av[0]), f2b(av[1]), f2b(av[2]), f2b(av[3])};
      *(bf16x4*)&As[r][ac0] = cv;
    }
    // stage B: bf16 W^T rows (n-major), 16B chunks
#pragma unroll
    for (int p = 0; p < 2; ++p) {
      const int idx = p * 256 + tid;
      const int r = idx >> 2, c8 = (idx & 3) * 8;
      *(u32x4*)&Bs[r][c8] = *(const u32x4*)&W[(size_t)(nbase + r) * 1024 + k0 + c8];
    }
    __syncthreads();

    bf16x8 af[4], bfr[4];
#pragma unroll
    for (int i = 0; i < 4; i++) af[i] = *(const bf16x8*)&As[wr * 64 + i * 16 + lr][kg * 8];
#pragma unroll
    for (int j = 0; j < 4; j++) bfr[j] = *(const bf16x8*)&Bs[wc * 64 + j * 16 + lr][kg * 8];
#pragma unroll
    for (int i = 0; i < 4; i++)
#pragma unroll
      for (int j = 0; j < 4; j++)
        acc[i][j] = MFMA(af[i], bfr[j], acc[i][j], 0, 0, 0);
    __syncthreads();
  }

  // epilogue: scatter to [b][h][s][dk] bf16
#pragma unroll
  for (int i = 0; i < 4; i++)
#pragma unroll
    for (int j = 0; j < 4; j++)
#pragma unroll
      for (int r = 0; r < 4; r++) {
        const int m = mbase + wr * 64 + i * 16 + kg * 4 + r;
        const int n = nbase + wc * 64 + j * 16 + lr;
        const int b = m >> 11, s = m & 2047, h = n >> 6, dk = n & 63;
        C[(((size_t)(b * 16 + h)) * 2048 + s) * 64 + dk] = f2b(acc[i][j][r]);
      }
}

// ---------------------------------------------------------------------------
// Causal flash attention. Q/K/V bf16 [B*H, 2048, 64]. Out -> AO bf16 [B,S,H*64].
// grid (16, 32): x = q-block (128 rows), y = b*16+h. block 256 (4 waves).
// Each wave: 32 q-rows. KV staged in 32-row blocks.
// ---------------------------------------------------------------------------
__global__ __launch_bounds__(256) void attn_kernel(
    const __bf16* __restrict__ Qh, const __bf16* __restrict__ Kh,
    const __bf16* __restrict__ Vh, __bf16* __restrict__ AO)
{
  const int bh = blockIdx.y;
  const int b = bh >> 4, h = bh & 15;
  const int qbase = blockIdx.x * 128;
  const size_t base = (size_t)bh * 2048 * 64;
  const __bf16* Qp = Qh + base;
  const __bf16* Kp = Kh + base;
  const __bf16* Vp = Vh + base;

  __shared__ __align__(16) __bf16 Ks[32][72];
  __shared__ __align__(16) __bf16 Vs[32][72];
  __shared__ __align__(16) __bf16 Ps[4][32][40];

  const int tid = threadIdx.x, wid = tid >> 6, lane = tid & 63;
  const int lr = lane & 15, kg = lane >> 4;
  const int wq = qbase + wid * 32;

  // preload Q fragments (reused across all KV blocks)
  bf16x8 qf[2][2];
#pragma unroll
  for (int rt = 0; rt < 2; rt++)
#pragma unroll
    for (int ks = 0; ks < 2; ks++)
      qf[rt][ks] = *(const bf16x8*)&Qp[(size_t)(wq + rt * 16 + lr) * 64 + ks * 32 + kg * 8];

  f32x4 o[2][4] = {};
  float mrow[2][4], lsum[2][4];
#pragma unroll
  for (int rt = 0; rt < 2; rt++)
#pragma unroll
    for (int r = 0; r < 4; r++) { mrow[rt][r] = -1e30f; lsum[rt][r] = 0.f; }

  const int srow = tid >> 3, sc8 = (tid & 7) * 8;
  const int nkv = (qbase + 128) >> 5;

  for (int kv = 0; kv < nkv; ++kv) {
    const int kbs = kv * 32;
    *(u32x4*)&Ks[srow][sc8] = *(const u32x4*)&Kp[(size_t)(kbs + srow) * 64 + sc8];
    *(u32x4*)&Vs[srow][sc8] = *(const u32x4*)&Vp[(size_t)(kbs + srow) * 64 + sc8];
    __syncthreads();

    // scores: S = Q K^T * 0.125
    f32x4 sc[2][2] = {};
#pragma unroll
    for (int ct = 0; ct < 2; ct++)
#pragma unroll
      for (int ks = 0; ks < 2; ks++) {
        bf16x8 kf = *(const bf16x8*)&Ks[ct * 16 + lr][ks * 32 + kg * 8];
#pragma unroll
        for (int rt = 0; rt < 2; rt++)
          sc[rt][ct] = MFMA(qf[rt][ks], kf, sc[rt][ct], 0, 0, 0);
      }

    // online softmax + write P to per-wave LDS
#pragma unroll
    for (int rt = 0; rt < 2; rt++) {
#pragma unroll
      for (int r = 0; r < 4; r++) {
        const int qidx = wq + rt * 16 + kg * 4 + r;
        float s0 = sc[rt][0][r] * 0.125f;
        float s1 = sc[rt][1][r] * 0.125f;
        if (kbs + lr > qidx) s0 = -1e30f;
        if (kbs + 16 + lr > qidx) s1 = -1e30f;
        float mx = fmaxf(s0, s1);
#pragma unroll
        for (int d = 1; d < 16; d <<= 1) mx = fmaxf(mx, __shfl_xor(mx, d, 16));
        const float mold = mrow[rt][r];
        const float mnew = fmaxf(mold, mx);
        const float scl = __expf(mold - mnew);
        const float p0 = __expf(s0 - mnew);
        const float p1 = __expf(s1 - mnew);
        float rs = p0 + p1;
#pragma unroll
        for (int d = 1; d < 16; d <<= 1) rs += __shfl_xor(rs, d, 16);
        lsum[rt][r] = lsum[rt][r] * scl + rs;
        mrow[rt][r] = mnew;
#pragma unroll
        for (int dvt = 0; dvt < 4; dvt++) o[rt][dvt][r] *= scl;
        Ps[wid][rt * 16 + kg * 4 + r][lr] = f2b(p0);
        Ps[wid][rt * 16 + kg * 4 + r][16 + lr] = f2b(p1);
      }
    }

    // PV: O += P * V
    bf16x8 vf[4];
#pragma unroll
    for (int dvt = 0; dvt < 4; dvt++) {
#pragma unroll
      for (int e = 0; e < 8; e++) vf[dvt][e] = Vs[kg * 8 + e][dvt * 16 + lr];
    }
#pragma unroll
    for (int rt = 0; rt < 2; rt++) {
      bf16x8 pa = *(const bf16x8*)&Ps[wid][rt * 16 + lr][kg * 8];
#pragma unroll
      for (int dvt = 0; dvt < 4; dvt++)
        o[rt][dvt] = MFMA(pa, vf[dvt], o[rt][dvt], 0, 0, 0);
    }
    __syncthreads();
  }

  // epilogue: AO[b][q][h*64+dv] = o / lsum
#pragma unroll
  for (int rt = 0; rt < 2; rt++)
#pragma unroll
    for (int dvt = 0; dvt < 4; dvt++)
#pragma unroll
      for (int r = 0; r < 4; r++) {
        const int qi = wq + rt * 16 + kg * 4 + r;
        const int dv = dvt * 16 + lr;
        const float val = o[rt][dvt][r] / lsum[rt][r];
        AO[((size_t)(b * 2048 + qi)) * 1024 + h * 64 + dv] = f2b(val);
      }
}

// ---------------------------------------------------------------------------
// Output GEMM: out(fp32 [4096,1024]) = AO(bf16 [4096,1024]) * Wo (bf16 Wo^T).
// grid 256, block 256. Same tiling as projection GEMM.
// ---------------------------------------------------------------------------
__global__ __launch_bounds__(256) void gemm_out_kernel(
    const __bf16* __restrict__ A, const __bf16* __restrict__ WT,
    float* __restrict__ Out)
{
  const int mt = blockIdx.x >> 3, nt = blockIdx.x & 7;
  const int mbase = mt * 128, nbase = nt * 128;

  __shared__ __align__(16) __bf16 As[128][40];
  __shared__ __align__(16) __bf16 Bs[128][40];

  const int tid = threadIdx.x;
  const int wid = tid >> 6, lane = tid & 63;
  const int wr = wid >> 1, wc = wid & 1;
  const int lr = lane & 15, kg = lane >> 4;

  f32x4 acc[4][4] = {};

  for (int kb = 0; kb < 32; ++kb) {
    const int k0 = kb * 32;
#pragma unroll
    for (int p = 0; p < 2; ++p) {
      const int idx = p * 256 + tid;
      const int r = idx >> 2, c8 = (idx & 3) * 8;
      *(u32x4*)&As[r][c8] = *(const u32x4*)&A[(size_t)(mbase + r) * 1024 + k0 + c8];
      *(u32x4*)&Bs[r][c8] = *(const u32x4*)&WT[(size_t)(nbase + r) * 1024 + k0 + c8];
    }
    __syncthreads();

    bf16x8 af[4], bfr[4];
#pragma unroll
    for (int i = 0; i < 4; i++) af[i] = *(const bf16x8*)&As[wr * 64 + i * 16 + lr][kg * 8];
#pragma unroll
    for (int j = 0; j < 4; j++) bfr[j] = *(const bf16x8*)&Bs[wc * 64 + j * 16 + lr][kg * 8];
#pragma unroll
    for (int i = 0; i < 4; i++)
#pragma unroll
      for (int j = 0; j < 4; j++)
        acc[i][j] = MFMA(af[i], bfr[j], acc[i][j], 0, 0, 0);
    __syncthreads();
  }

#pragma unroll
  for (int i = 0; i < 4; i++)
#pragma unroll
    for (int j = 0; j < 4; j++)
#pragma unroll
      for (int r = 0; r < 4; r++) {
        const int m = mbase + wr * 64 + i * 16 + kg * 4 + r;
        const int n = nbase + wc * 64 + j * 16 + lr;
        Out[(size_t)m * 1024 + n] = acc[i][j][r];
      }
}

// ---------------------------------------------------------------------------
extern "C" void kernel_launch(void* const* d_in, const int* in_sizes, int n_in,
                              void* d_out, int out_size, void* d_ws, size_t ws_size,
                              hipStream_t stream) {
  const float* Q  = (const float*)d_in[0];
  const float* K  = (const float*)d_in[1];
  const float* V  = (const float*)d_in[2];
  const float* Wq = (const float*)d_in[3];
  const float* Wk = (const float*)d_in[4];
  const float* Wv = (const float*)d_in[5];
  const float* Wo = (const float*)d_in[6];
  float* out = (float*)d_out;

  // ws layout (bf16 elems): wT[4*1M] | q[4M] | k[4M] | v[4M] | ao[4M]
  __bf16* wT = (__bf16*)d_ws;
  __bf16* qb = wT + (size_t)4 * 1048576;
  __bf16* kb = qb + (size_t)4194304;
  __bf16* vb = kb + (size_t)4194304;
  __bf16* ao = vb + (size_t)4194304;

  wtrans_kernel<<<dim3(32, 32, 4), 256, 0, stream>>>(Wq, Wk, Wv, Wo, wT);
  gemm_proj_kernel<<<dim3(256, 3), 256, 0, stream>>>(Q, K, V, wT, qb, kb, vb);
  attn_kernel<<<dim3(16, 32), 256, 0, stream>>>(qb, kb, vb, ao);
  gemm_out_kernel<<<dim3(256), 256, 0, stream>>>(ao, wT + (size_t)3 * 1048576, out);
}

// Round 2
// 220.043 us; speedup vs baseline: 1.3045x; 1.3045x over previous
//
#include <hip/hip_runtime.h>
#include <cstdint>
#include <cstddef>

// MHA: B=2, S=2048, D=1024, H=16, DK=DV=64, causal, scale=1/8 on scores.
// Pipeline: (1) weights -> bf16 W^T, (2) Q/K/V projections (bf16 MFMA GEMM),
// (3) causal flash attention (swapped-operand form), (4) output GEMM -> fp32.

typedef __bf16 bf16x8 __attribute__((ext_vector_type(8)));
typedef __bf16 bf16x4 __attribute__((ext_vector_type(4)));
typedef float f32x4 __attribute__((ext_vector_type(4)));
typedef unsigned int u32x4 __attribute__((ext_vector_type(4)));

#define MFMA __builtin_amdgcn_mfma_f32_16x16x32_bf16

static __device__ __forceinline__ __bf16 f2b(float f) { return (__bf16)f; }

// ---------------------------------------------------------------------------
// Weight transpose+convert: O[n][k] = (bf16) W[k][n], each 1024x1024.
// ---------------------------------------------------------------------------
__global__ __launch_bounds__(256) void wtrans_kernel(
    const float* __restrict__ w0, const float* __restrict__ w1,
    const float* __restrict__ w2, const float* __restrict__ w3,
    __bf16* __restrict__ outT)
{
  const int z = blockIdx.z;
  const float* W = (z == 0) ? w0 : (z == 1) ? w1 : (z == 2) ? w2 : w3;
  __bf16* O = outT + (size_t)z * 1048576;
  __shared__ float t[32][33];
  const int tx = threadIdx.x & 31, ty = threadIdx.x >> 5;  // ty 0..7
  const int kb = blockIdx.y * 32, nb = blockIdx.x * 32;
#pragma unroll
  for (int i = 0; i < 4; i++)
    t[ty + i * 8][tx] = W[(size_t)(kb + ty + i * 8) * 1024 + nb + tx];
  __syncthreads();
#pragma unroll
  for (int i = 0; i < 4; i++)
    O[(size_t)(nb + ty + i * 8) * 1024 + kb + tx] = f2b(t[tx][ty + i * 8]);
}

// ---------------------------------------------------------------------------
// Projection GEMM: C = A(fp32 [4096,1024]) * W(bf16 W^T layout [1024n][1024k])
// Output bf16 scattered to [B=2, H=16, S=2048, 64] head-major.
// ---------------------------------------------------------------------------
__global__ __launch_bounds__(256) void gemm_proj_kernel(
    const float* __restrict__ A0, const float* __restrict__ A1,
    const float* __restrict__ A2, const __bf16* __restrict__ WT,
    __bf16* __restrict__ C0, __bf16* __restrict__ C1, __bf16* __restrict__ C2)
{
  const int z = blockIdx.y;
  const float* A = (z == 0) ? A0 : (z == 1) ? A1 : A2;
  const __bf16* W = WT + (size_t)z * 1048576;
  __bf16* C = (z == 0) ? C0 : (z == 1) ? C1 : C2;

  const int mt = blockIdx.x >> 3, nt = blockIdx.x & 7;
  const int mbase = mt * 128, nbase = nt * 128;

  __shared__ __align__(16) __bf16 As[128][40];
  __shared__ __align__(16) __bf16 Bs[128][40];

  const int tid = threadIdx.x;
  const int wid = tid >> 6, lane = tid & 63;
  const int wr = wid >> 1, wc = wid & 1;
  const int lr = lane & 15, kg = lane >> 4;

  f32x4 acc[4][4] = {};

  const int arow = tid >> 3, ac0 = (tid & 7) * 4;

  for (int kb = 0; kb < 32; ++kb) {
    const int k0 = kb * 32;
#pragma unroll
    for (int p = 0; p < 4; ++p) {
      const int r = arow + p * 32;
      f32x4 av = *(const f32x4*)&A[(size_t)(mbase + r) * 1024 + k0 + ac0];
      bf16x4 cv = {f2b(av[0]), f2b(av[1]), f2b(av[2]), f2b(av[3])};
      *(bf16x4*)&As[r][ac0] = cv;
    }
#pragma unroll
    for (int p = 0; p < 2; ++p) {
      const int idx = p * 256 + tid;
      const int r = idx >> 2, c8 = (idx & 3) * 8;
      *(u32x4*)&Bs[r][c8] = *(const u32x4*)&W[(size_t)(nbase + r) * 1024 + k0 + c8];
    }
    __syncthreads();

    bf16x8 af[4], bfr[4];
#pragma unroll
    for (int i = 0; i < 4; i++) af[i] = *(const bf16x8*)&As[wr * 64 + i * 16 + lr][kg * 8];
#pragma unroll
    for (int j = 0; j < 4; j++) bfr[j] = *(const bf16x8*)&Bs[wc * 64 + j * 16 + lr][kg * 8];
#pragma unroll
    for (int i = 0; i < 4; i++)
#pragma unroll
      for (int j = 0; j < 4; j++)
        acc[i][j] = MFMA(af[i], bfr[j], acc[i][j], 0, 0, 0);
    __syncthreads();
  }

#pragma unroll
  for (int i = 0; i < 4; i++)
#pragma unroll
    for (int j = 0; j < 4; j++)
#pragma unroll
      for (int r = 0; r < 4; r++) {
        const int m = mbase + wr * 64 + i * 16 + kg * 4 + r;
        const int n = nbase + wc * 64 + j * 16 + lr;
        const int b = m >> 11, s = m & 2047, h = n >> 6, dk = n & 63;
        C[(((size_t)(b * 16 + h)) * 2048 + s) * 64 + dk] = f2b(acc[i][j][r]);
      }
}

// ---------------------------------------------------------------------------
// Causal flash attention, swapped-operand form.
// Q/K/V bf16 [B*H, 2048, 64]. Out -> AO bf16 [B,S,H*64].
// grid (16, 32): x = q-block (128 rows, REVERSED), y = b*16+h. block 256.
// Per wave: 32 q rows. KVB = 64.
//  S^T = K Q^T  (C: row=kv, col=q=lane&15)  -> softmax lane-local + 2 shfl
//  O^T = V^T P^T (A=Vt rows b128, B=P^T from LDS b128; q stays = lane&15)
// ---------------------------------------------------------------------------
__global__ __launch_bounds__(256) void attn_kernel(
    const __bf16* __restrict__ Qh, const __bf16* __restrict__ Kh,
    const __bf16* __restrict__ Vh, __bf16* __restrict__ AO)
{
  const int bh = blockIdx.y;
  const int b = bh >> 4, h = bh & 15;
  const int qblk = 15 - blockIdx.x;       // heavy blocks dispatch first
  const int qbase = qblk * 128;
  const size_t base = (size_t)bh * 2048 * 64;
  const __bf16* Qp = Qh + base;
  const __bf16* Kp = Kh + base;
  const __bf16* Vp = Vh + base;

  __shared__ __align__(16) __bf16 Ks[64][72];   // K rows
  __shared__ __align__(16) __bf16 Vt[64][72];   // V transposed: Vt[dv][kv]
  __shared__ __align__(16) __bf16 Ps[4][32][72];// per-wave P: Ps[w][q][kv]

  const int tid = threadIdx.x, wid = tid >> 6, lane = tid & 63;
  const int lr = lane & 15, kg = lane >> 4;
  const int wq = qbase + wid * 32;

  // Q fragments (B-operand layout == same addresses as A-layout load)
  bf16x8 qf[2][2];
#pragma unroll
  for (int qt = 0; qt < 2; qt++)
#pragma unroll
    for (int ks = 0; ks < 2; ks++)
      qf[qt][ks] = *(const bf16x8*)&Qp[(size_t)(wq + qt * 16 + lr) * 64 + ks * 32 + kg * 8];

  // O^T accum: ot[qt][dvt], lane holds dv = dvt*16+kg*4+r, q = qt*16+lr
  f32x4 ot[2][4] = {};
  float mrow[2] = {-1e30f, -1e30f};
  float lsum[2] = {0.f, 0.f};

  const float SCALE = 0.125f * 1.44269504f;  // 1/sqrt(64) * log2(e)

  const int srow = tid >> 3, sg = tid & 7, sc8 = sg * 8;
  const int nkv = (qbase + 128) >> 6;

  for (int kv = 0; kv < nkv; ++kv) {
    const int kv0 = kv * 64;
    // stage K (row-major) and V (transposed, rotated scatter: 2-way conflicts)
#pragma unroll
    for (int p = 0; p < 2; ++p) {
      const int r = srow + p * 32;
      *(u32x4*)&Ks[r][sc8] = *(const u32x4*)&Kp[(size_t)(kv0 + r) * 64 + sc8];
      u32x4 vv = *(const u32x4*)&Vp[(size_t)(kv0 + r) * 64 + sc8];
      const __bf16* ve = (const __bf16*)&vv;
#pragma unroll
      for (int e = 0; e < 8; ++e) {
        const int hsh = (e + r + sg) & 7;
        Vt[sc8 + hsh][r] = ve[hsh];
      }
    }
    __syncthreads();

    if (kv0 <= wq + 31) {  // wave has unmasked work in this KV block
      // S^T = K Q^T
      f32x4 st[4][2] = {};
#pragma unroll
      for (int kvt = 0; kvt < 4; ++kvt)
#pragma unroll
        for (int ks = 0; ks < 2; ++ks) {
          bf16x8 kf = *(const bf16x8*)&Ks[kvt * 16 + lr][ks * 32 + kg * 8];
#pragma unroll
          for (int qt = 0; qt < 2; ++qt)
            st[kvt][qt] = MFMA(kf, qf[qt][ks], st[kvt][qt], 0, 0, 0);
        }

      const bool needmask = (kv0 + 63 > wq);
#pragma unroll
      for (int qt = 0; qt < 2; ++qt) {
        const int qidx = wq + qt * 16 + lr;
        float s[4][4];
        float mx = -1e30f;
#pragma unroll
        for (int kvt = 0; kvt < 4; ++kvt)
#pragma unroll
          for (int r = 0; r < 4; ++r) {
            float v = st[kvt][qt][r] * SCALE;
            if (needmask && (kv0 + kvt * 16 + kg * 4 + r > qidx)) v = -1e30f;
            s[kvt][r] = v;
            mx = fmaxf(mx, v);
          }
        mx = fmaxf(mx, __shfl_xor(mx, 16));
        mx = fmaxf(mx, __shfl_xor(mx, 32));
        const float mnew = fmaxf(mrow[qt], mx);
        const float scl = exp2f(mrow[qt] - mnew);
        mrow[qt] = mnew;
        float rs = 0.f;
#pragma unroll
        for (int kvt = 0; kvt < 4; ++kvt) {
          bf16x4 pk;
#pragma unroll
          for (int r = 0; r < 4; ++r) {
            const float p = exp2f(s[kvt][r] - mnew);
            rs += p;
            pk[r] = f2b(p);
          }
          *(bf16x4*)&Ps[wid][qt * 16 + lr][kvt * 16 + kg * 4] = pk;  // b64
        }
        rs += __shfl_xor(rs, 16);
        rs += __shfl_xor(rs, 32);
        lsum[qt] = lsum[qt] * scl + rs;
#pragma unroll
        for (int dvt = 0; dvt < 4; ++dvt) ot[qt][dvt] *= scl;
      }

      // O^T += V^T P^T
#pragma unroll
      for (int ks2 = 0; ks2 < 2; ++ks2) {
        bf16x8 pf[2];
#pragma unroll
        for (int qt = 0; qt < 2; ++qt)
          pf[qt] = *(const bf16x8*)&Ps[wid][qt * 16 + lr][ks2 * 32 + kg * 8];
#pragma unroll
        for (int dvt = 0; dvt < 4; ++dvt) {
          bf16x8 vf = *(const bf16x8*)&Vt[dvt * 16 + lr][ks2 * 32 + kg * 8];
#pragma unroll
          for (int qt = 0; qt < 2; ++qt)
            ot[qt][dvt] = MFMA(vf, pf[qt], ot[qt][dvt], 0, 0, 0);
        }
      }
    }
    __syncthreads();
  }

  // epilogue: AO[b][q][h*64+dv] = ot / lsum, packed b64 stores
#pragma unroll
  for (int qt = 0; qt < 2; ++qt) {
    const float rl = 1.f / lsum[qt];
    const int q = wq + qt * 16 + lr;
#pragma unroll
    for (int dvt = 0; dvt < 4; ++dvt) {
      bf16x4 w;
#pragma unroll
      for (int r = 0; r < 4; ++r) w[r] = f2b(ot[qt][dvt][r] * rl);
      *(bf16x4*)&AO[((size_t)(b * 2048 + q)) * 1024 + h * 64 + dvt * 16 + kg * 4] = w;
    }
  }
}

// ---------------------------------------------------------------------------
// Output GEMM: out(fp32 [4096,1024]) = AO(bf16 [4096,1024]) * Wo (bf16 Wo^T).
// ---------------------------------------------------------------------------
__global__ __launch_bounds__(256) void gemm_out_kernel(
    const __bf16* __restrict__ A, const __bf16* __restrict__ WT,
    float* __restrict__ Out)
{
  const int mt = blockIdx.x >> 3, nt = blockIdx.x & 7;
  const int mbase = mt * 128, nbase = nt * 128;

  __shared__ __align__(16) __bf16 As[128][40];
  __shared__ __align__(16) __bf16 Bs[128][40];

  const int tid = threadIdx.x;
  const int wid = tid >> 6, lane = tid & 63;
  const int wr = wid >> 1, wc = wid & 1;
  const int lr = lane & 15, kg = lane >> 4;

  f32x4 acc[4][4] = {};

  for (int kb = 0; kb < 32; ++kb) {
    const int k0 = kb * 32;
#pragma unroll
    for (int p = 0; p < 2; ++p) {
      const int idx = p * 256 + tid;
      const int r = idx >> 2, c8 = (idx & 3) * 8;
      *(u32x4*)&As[r][c8] = *(const u32x4*)&A[(size_t)(mbase + r) * 1024 + k0 + c8];
      *(u32x4*)&Bs[r][c8] = *(const u32x4*)&WT[(size_t)(nbase + r) * 1024 + k0 + c8];
    }
    __syncthreads();

    bf16x8 af[4], bfr[4];
#pragma unroll
    for (int i = 0; i < 4; i++) af[i] = *(const bf16x8*)&As[wr * 64 + i * 16 + lr][kg * 8];
#pragma unroll
    for (int j = 0; j < 4; j++) bfr[j] = *(const bf16x8*)&Bs[wc * 64 + j * 16 + lr][kg * 8];
#pragma unroll
    for (int i = 0; i < 4; i++)
#pragma unroll
      for (int j = 0; j < 4; j++)
        acc[i][j] = MFMA(af[i], bfr[j], acc[i][j], 0, 0, 0);
    __syncthreads();
  }

#pragma unroll
  for (int i = 0; i < 4; i++)
#pragma unroll
    for (int j = 0; j < 4; j++)
#pragma unroll
      for (int r = 0; r < 4; r++) {
        const int m = mbase + wr * 64 + i * 16 + kg * 4 + r;
        const int n = nbase + wc * 64 + j * 16 + lr;
        Out[(size_t)m * 1024 + n] = acc[i][j][r];
      }
}

// ---------------------------------------------------------------------------
extern "C" void kernel_launch(void* const* d_in, const int* in_sizes, int n_in,
                              void* d_out, int out_size, void* d_ws, size_t ws_size,
                              hipStream_t stream) {
  const float* Q  = (const float*)d_in[0];
  const float* K  = (const float*)d_in[1];
  const float* V  = (const float*)d_in[2];
  const float* Wq = (const float*)d_in[3];
  const float* Wk = (const float*)d_in[4];
  const float* Wv = (const float*)d_in[5];
  const float* Wo = (const float*)d_in[6];
  float* out = (float*)d_out;

  __bf16* wT = (__bf16*)d_ws;
  __bf16* qb = wT + (size_t)4 * 1048576;
  __bf16* kb = qb + (size_t)4194304;
  __bf16* vb = kb + (size_t)4194304;
  __bf16* ao = vb + (size_t)4194304;

  wtrans_kernel<<<dim3(32, 32, 4), 256, 0, stream>>>(Wq, Wk, Wv, Wo, wT);
  gemm_proj_kernel<<<dim3(256, 3), 256, 0, stream>>>(Q, K, V, wT, qb, kb, vb);
  attn_kernel<<<dim3(16, 32), 256, 0, stream>>>(qb, kb, vb, ao);
  gemm_out_kernel<<<dim3(256), 256, 0, stream>>>(ao, wT + (size_t)3 * 1048576, out);
}

// Round 5
// 153.290 us; speedup vs baseline: 1.8725x; 1.4355x over previous
//
#include <hip/hip_runtime.h>
#include <cstdint>
#include <cstddef>

// MHA: B=2, S=2048, D=1024, H=16, DK=DV=64, causal, scale=1/8 on scores.
// Pipeline: (1) weights -> bf16 W^T, (2) Q/K/V projections (bf16 MFMA GEMM;
// V written TRANSPOSED per head), (3) causal flash attention (swapped ops,
// verified LDS P-bounce, plain b128 V^T reads, dbuf), (4) output GEMM -> fp32.

typedef __bf16 bf16x8 __attribute__((ext_vector_type(8)));
typedef __bf16 bf16x4 __attribute__((ext_vector_type(4)));
typedef float f32x4 __attribute__((ext_vector_type(4)));
typedef unsigned int u32x4 __attribute__((ext_vector_type(4)));

#define MFMA __builtin_amdgcn_mfma_f32_16x16x32_bf16

static __device__ __forceinline__ __bf16 f2b(float f) { return (__bf16)f; }

// ---------------------------------------------------------------------------
// Weight transpose+convert: O[n][k] = (bf16) W[k][n], each 1024x1024.
// ---------------------------------------------------------------------------
__global__ __launch_bounds__(256) void wtrans_kernel(
    const float* __restrict__ w0, const float* __restrict__ w1,
    const float* __restrict__ w2, const float* __restrict__ w3,
    __bf16* __restrict__ outT)
{
  const int z = blockIdx.z;
  const float* W = (z == 0) ? w0 : (z == 1) ? w1 : (z == 2) ? w2 : w3;
  __bf16* O = outT + (size_t)z * 1048576;
  __shared__ float t[32][33];
  const int tx = threadIdx.x & 31, ty = threadIdx.x >> 5;
  const int kb = blockIdx.y * 32, nb = blockIdx.x * 32;
#pragma unroll
  for (int i = 0; i < 4; i++)
    t[ty + i * 8][tx] = W[(size_t)(kb + ty + i * 8) * 1024 + nb + tx];
  __syncthreads();
#pragma unroll
  for (int i = 0; i < 4; i++)
    O[(size_t)(nb + ty + i * 8) * 1024 + kb + tx] = f2b(t[tx][ty + i * 8]);
}

// ---------------------------------------------------------------------------
// Projection GEMM: C = A(fp32 [4096,1024]) * W^T(bf16).
// z=0 (Q), z=1 (K): scatter to [b,h,s,dk] head-major bf16.
// z=2 (V): write TRANSPOSED per head: VT[(b*16+h)*64 + dv][s], packed bf16x4
//          along s (lane holds 4 consecutive m=s for fixed n=dv).
// ---------------------------------------------------------------------------
__global__ __launch_bounds__(256) void gemm_proj_kernel(
    const float* __restrict__ A0, const float* __restrict__ A1,
    const float* __restrict__ A2, const __bf16* __restrict__ WT,
    __bf16* __restrict__ C0, __bf16* __restrict__ C1, __bf16* __restrict__ C2)
{
  const int z = blockIdx.y;
  const float* A = (z == 0) ? A0 : (z == 1) ? A1 : A2;
  const __bf16* W = WT + (size_t)z * 1048576;
  __bf16* C = (z == 0) ? C0 : (z == 1) ? C1 : C2;

  const int mt = blockIdx.x >> 3, nt = blockIdx.x & 7;
  const int mbase = mt * 128, nbase = nt * 128;

  __shared__ __align__(16) __bf16 As[128][40];
  __shared__ __align__(16) __bf16 Bs[128][40];

  const int tid = threadIdx.x;
  const int wid = tid >> 6, lane = tid & 63;
  const int wr = wid >> 1, wc = wid & 1;
  const int lr = lane & 15, kg = lane >> 4;

  f32x4 acc[4][4] = {};

  const int arow = tid >> 3, ac0 = (tid & 7) * 4;

  for (int kb = 0; kb < 32; ++kb) {
    const int k0 = kb * 32;
#pragma unroll
    for (int p = 0; p < 4; ++p) {
      const int r = arow + p * 32;
      f32x4 av = *(const f32x4*)&A[(size_t)(mbase + r) * 1024 + k0 + ac0];
      bf16x4 cv = {f2b(av[0]), f2b(av[1]), f2b(av[2]), f2b(av[3])};
      *(bf16x4*)&As[r][ac0] = cv;
    }
#pragma unroll
    for (int p = 0; p < 2; ++p) {
      const int idx = p * 256 + tid;
      const int r = idx >> 2, c8 = (idx & 3) * 8;
      *(u32x4*)&Bs[r][c8] = *(const u32x4*)&W[(size_t)(nbase + r) * 1024 + k0 + c8];
    }
    __syncthreads();

    bf16x8 af[4], bfr[4];
#pragma unroll
    for (int i = 0; i < 4; i++) af[i] = *(const bf16x8*)&As[wr * 64 + i * 16 + lr][kg * 8];
#pragma unroll
    for (int j = 0; j < 4; j++) bfr[j] = *(const bf16x8*)&Bs[wc * 64 + j * 16 + lr][kg * 8];
#pragma unroll
    for (int i = 0; i < 4; i++)
#pragma unroll
      for (int j = 0; j < 4; j++)
        acc[i][j] = MFMA(af[i], bfr[j], acc[i][j], 0, 0, 0);
    __syncthreads();
  }

  if (z == 2) {
    // V^T epilogue: packed 4-consecutive-s stores.
#pragma unroll
    for (int i = 0; i < 4; i++)
#pragma unroll
      for (int j = 0; j < 4; j++) {
        const int m0 = mbase + wr * 64 + i * 16 + kg * 4;
        const int n = nbase + wc * 64 + j * 16 + lr;
        const int b = m0 >> 11, s = m0 & 2047, h = n >> 6, dv = n & 63;
        bf16x4 w;
#pragma unroll
        for (int r = 0; r < 4; r++) w[r] = f2b(acc[i][j][r]);
        *(bf16x4*)&C[(((size_t)(b * 16 + h)) * 64 + dv) * 2048 + s] = w;
      }
  } else {
#pragma unroll
    for (int i = 0; i < 4; i++)
#pragma unroll
      for (int j = 0; j < 4; j++)
#pragma unroll
        for (int r = 0; r < 4; r++) {
          const int m = mbase + wr * 64 + i * 16 + kg * 4 + r;
          const int n = nbase + wc * 64 + j * 16 + lr;
          const int b = m >> 11, s = m & 2047, h = n >> 6, dk = n & 63;
          C[(((size_t)(b * 16 + h)) * 2048 + s) * 64 + dk] = f2b(acc[i][j][r]);
        }
  }
}

// ---------------------------------------------------------------------------
// Causal flash attention v4.
// Q/K bf16 [B*H, 2048, 64]; V^T bf16 [B*H, 64, 2048]. Out -> AO [B,S,H*64].
// grid (16,32) remapped for XCD locality; block 256 (4 waves).
// Each block: paired q-blocks (x, 31-x), QBLK=64 (16 q-rows/wave), KVB=64.
// S^T = K Q^T -> softmax lane-local (+2 shfl); P via per-wave LDS bounce
// (verified round-2 mechanism); PV A-frags = plain b128 reads of staged V^T.
// K/V^T double-buffered, reg-prefetch, 1 barrier/iter.
// ---------------------------------------------------------------------------
__global__ __launch_bounds__(256) void attn_kernel(
    const __bf16* __restrict__ Qh, const __bf16* __restrict__ Kh,
    const __bf16* __restrict__ VTh, __bf16* __restrict__ AO)
{
  const int lin = blockIdx.y * 16 + blockIdx.x;
  const int l = (lin & 7) * 64 + (lin >> 3);   // XCD-contiguous remap (512%8==0)
  const int xp = l & 15, bh = l >> 4;
  const int b = bh >> 4, h = bh & 15;
  const __bf16* Qp = Qh + (size_t)bh * 2048 * 64;
  const __bf16* Kp = Kh + (size_t)bh * 2048 * 64;
  const __bf16* Vp = VTh + (size_t)bh * 64 * 2048;   // V^T rows = dv

  __shared__ __align__(16) __bf16 Ks[2][64][72];
  __shared__ __align__(16) __bf16 Vt[2][64][72];   // Vt[dv][kv-within-tile]
  __shared__ __align__(16) __bf16 Ps[4][16][72];   // per-wave P: [q][kv]

  const int tid = threadIdx.x, wid = tid >> 6, lane = tid & 63;
  const int lr = lane & 15, kg = lane >> 4;
  const int sr0 = tid >> 3, sc0 = (tid & 7) * 8;
  const float SCALE = 0.125f * 1.44269504f;

#pragma unroll
  for (int phase = 0; phase < 2; ++phase) {
    const int qblk = phase ? (31 - xp) : xp;
    const int qbase = qblk << 6;
    const int nkv = qblk + 1;
    const int wq = qbase + wid * 16;

    bf16x8 qf0 = *(const bf16x8*)&Qp[(size_t)(wq + lr) * 64 + kg * 8];
    bf16x8 qf1 = *(const bf16x8*)&Qp[(size_t)(wq + lr) * 64 + 32 + kg * 8];

    f32x4 ot[4] = {};
    float mrow = -1e30f, lsum = 0.f;

    // stage tile 0 (K rows; V^T rows along kv)
    u32x4 kr0 = *(const u32x4*)&Kp[(size_t)sr0 * 64 + sc0];
    u32x4 kr1 = *(const u32x4*)&Kp[(size_t)(sr0 + 32) * 64 + sc0];
    u32x4 vr0 = *(const u32x4*)&Vp[(size_t)sr0 * 2048 + sc0];
    u32x4 vr1 = *(const u32x4*)&Vp[(size_t)(sr0 + 32) * 2048 + sc0];
    __syncthreads();   // prior phase done reading LDS
    *(u32x4*)&Ks[0][sr0][sc0] = kr0;
    *(u32x4*)&Ks[0][sr0 + 32][sc0] = kr1;
    *(u32x4*)&Vt[0][sr0][sc0] = vr0;
    *(u32x4*)&Vt[0][sr0 + 32][sc0] = vr1;

    int cur = 0;
    for (int t = 0; t < nkv; ++t) {
      const int kv0 = t << 6;
      const bool pre = (t + 1 < nkv);
      if (pre) {
        const int nkv0 = kv0 + 64;
        kr0 = *(const u32x4*)&Kp[(size_t)(nkv0 + sr0) * 64 + sc0];
        kr1 = *(const u32x4*)&Kp[(size_t)(nkv0 + sr0 + 32) * 64 + sc0];
        vr0 = *(const u32x4*)&Vp[(size_t)sr0 * 2048 + nkv0 + sc0];
        vr1 = *(const u32x4*)&Vp[(size_t)(sr0 + 32) * 2048 + nkv0 + sc0];
      }
      __syncthreads();

      if (kv0 <= wq + 15) {
        // ---- S^T = K Q^T ----
        f32x4 st[4] = {};
        __builtin_amdgcn_s_setprio(1);
#pragma unroll
        for (int kvt = 0; kvt < 4; ++kvt) {
          bf16x8 kf0 = *(const bf16x8*)&Ks[cur][kvt * 16 + lr][kg * 8];
          bf16x8 kf1 = *(const bf16x8*)&Ks[cur][kvt * 16 + lr][32 + kg * 8];
          st[kvt] = MFMA(kf0, qf0, st[kvt], 0, 0, 0);
          st[kvt] = MFMA(kf1, qf1, st[kvt], 0, 0, 0);
        }
        __builtin_amdgcn_s_setprio(0);

        // ---- online softmax (lane-local over 16 kv + 2 shfl) ----
        const int qidx = wq + lr;
        const bool needmask = (kv0 + 63) > wq;
        float sv[16];
        float mx = -1e30f;
#pragma unroll
        for (int kvt = 0; kvt < 4; ++kvt)
#pragma unroll
          for (int r = 0; r < 4; ++r) {
            float v = st[kvt][r] * SCALE;
            if (needmask && (kv0 + kvt * 16 + kg * 4 + r > qidx)) v = -1e30f;
            sv[kvt * 4 + r] = v;
            mx = fmaxf(mx, v);
          }
        mx = fmaxf(mx, __shfl_xor(mx, 16));
        mx = fmaxf(mx, __shfl_xor(mx, 32));
        const float mnew = fmaxf(mrow, mx);
        const float scl = exp2f(mrow - mnew);
        mrow = mnew;
        float rs = 0.f;
#pragma unroll
        for (int kvt = 0; kvt < 4; ++kvt) {
          bf16x4 pk;
#pragma unroll
          for (int r = 0; r < 4; ++r) {
            const float p = exp2f(sv[kvt * 4 + r] - mnew);
            rs += p;
            pk[r] = f2b(p);
          }
          *(bf16x4*)&Ps[wid][lr][kvt * 16 + kg * 4] = pk;  // b64 write
        }
        rs += __shfl_xor(rs, 16);
        rs += __shfl_xor(rs, 32);
        lsum = lsum * scl + rs;
#pragma unroll
        for (int dvt = 0; dvt < 4; ++dvt) ot[dvt] *= scl;

        // ---- O^T += V^T P^T (plain b128 fragment reads) ----
#pragma unroll
        for (int h2 = 0; h2 < 2; ++h2) {
          bf16x8 pf = *(const bf16x8*)&Ps[wid][lr][h2 * 32 + kg * 8];
          __builtin_amdgcn_s_setprio(1);
#pragma unroll
          for (int dvt = 0; dvt < 4; ++dvt) {
            bf16x8 vf = *(const bf16x8*)&Vt[cur][dvt * 16 + lr][h2 * 32 + kg * 8];
            ot[dvt] = MFMA(vf, pf, ot[dvt], 0, 0, 0);
          }
          __builtin_amdgcn_s_setprio(0);
        }
      }

      if (pre) {
        const int nb = cur ^ 1;
        *(u32x4*)&Ks[nb][sr0][sc0] = kr0;
        *(u32x4*)&Ks[nb][sr0 + 32][sc0] = kr1;
        *(u32x4*)&Vt[nb][sr0][sc0] = vr0;
        *(u32x4*)&Vt[nb][sr0 + 32][sc0] = vr1;
      }
      cur ^= 1;
    }

    // epilogue: AO[b][q][h*64+dv] = ot / lsum, packed b64 stores
    const float rl = 1.f / lsum;
    const int q = wq + lr;
#pragma unroll
    for (int dvt = 0; dvt < 4; ++dvt) {
      bf16x4 w;
#pragma unroll
      for (int r = 0; r < 4; ++r) w[r] = f2b(ot[dvt][r] * rl);
      *(bf16x4*)&AO[((size_t)(b * 2048 + q)) * 1024 + h * 64 + dvt * 16 + kg * 4] = w;
    }
  }
}

// ---------------------------------------------------------------------------
// Output GEMM: out(fp32 [4096,1024]) = AO(bf16) * Wo^T (bf16).
// ---------------------------------------------------------------------------
__global__ __launch_bounds__(256) void gemm_out_kernel(
    const __bf16* __restrict__ A, const __bf16* __restrict__ WT,
    float* __restrict__ Out)
{
  const int mt = blockIdx.x >> 3, nt = blockIdx.x & 7;
  const int mbase = mt * 128, nbase = nt * 128;

  __shared__ __align__(16) __bf16 As[128][40];
  __shared__ __align__(16) __bf16 Bs[128][40];

  const int tid = threadIdx.x;
  const int wid = tid >> 6, lane = tid & 63;
  const int wr = wid >> 1, wc = wid & 1;
  const int lr = lane & 15, kg = lane >> 4;

  f32x4 acc[4][4] = {};

  for (int kb = 0; kb < 32; ++kb) {
    const int k0 = kb * 32;
#pragma unroll
    for (int p = 0; p < 2; ++p) {
      const int idx = p * 256 + tid;
      const int r = idx >> 2, c8 = (idx & 3) * 8;
      *(u32x4*)&As[r][c8] = *(const u32x4*)&A[(size_t)(mbase + r) * 1024 + k0 + c8];
      *(u32x4*)&Bs[r][c8] = *(const u32x4*)&WT[(size_t)(nbase + r) * 1024 + k0 + c8];
    }
    __syncthreads();

    bf16x8 af[4], bfr[4];
#pragma unroll
    for (int i = 0; i < 4; i++) af[i] = *(const bf16x8*)&As[wr * 64 + i * 16 + lr][kg * 8];
#pragma unroll
    for (int j = 0; j < 4; j++) bfr[j] = *(const bf16x8*)&Bs[wc * 64 + j * 16 + lr][kg * 8];
#pragma unroll
    for (int i = 0; i < 4; i++)
#pragma unroll
      for (int j = 0; j < 4; j++)
        acc[i][j] = MFMA(af[i], bfr[j], acc[i][j], 0, 0, 0);
    __syncthreads();
  }

#pragma unroll
  for (int i = 0; i < 4; i++)
#pragma unroll
    for (int j = 0; j < 4; j++)
#pragma unroll
      for (int r = 0; r < 4; r++) {
        const int m = mbase + wr * 64 + i * 16 + kg * 4 + r;
        const int n = nbase + wc * 64 + j * 16 + lr;
        Out[(size_t)m * 1024 + n] = acc[i][j][r];
      }
}

// ---------------------------------------------------------------------------
extern "C" void kernel_launch(void* const* d_in, const int* in_sizes, int n_in,
                              void* d_out, int out_size, void* d_ws, size_t ws_size,
                              hipStream_t stream) {
  const float* Q  = (const float*)d_in[0];
  const float* K  = (const float*)d_in[1];
  const float* V  = (const float*)d_in[2];
  const float* Wq = (const float*)d_in[3];
  const float* Wk = (const float*)d_in[4];
  const float* Wv = (const float*)d_in[5];
  const float* Wo = (const float*)d_in[6];
  float* out = (float*)d_out;

  // ws layout (bf16 elems): wT[4*1M] | q[4M] | k[4M] | vT[4M] | ao[4M]
  __bf16* wT  = (__bf16*)d_ws;
  __bf16* qb  = wT + (size_t)4 * 1048576;
  __bf16* kb  = qb + (size_t)4194304;
  __bf16* vtb = kb + (size_t)4194304;
  __bf16* ao  = vtb + (size_t)4194304;

  wtrans_kernel<<<dim3(32, 32, 4), 256, 0, stream>>>(Wq, Wk, Wv, Wo, wT);
  gemm_proj_kernel<<<dim3(256, 3), 256, 0, stream>>>(Q, K, V, wT, qb, kb, vtb);
  attn_kernel<<<dim3(16, 32), 256, 0, stream>>>(qb, kb, vtb, ao);
  gemm_out_kernel<<<dim3(256), 256, 0, stream>>>(ao, wT + (size_t)3 * 1048576, out);
}

// Round 6
// 137.841 us; speedup vs baseline: 2.0824x; 1.1121x over previous
//
#include <hip/hip_runtime.h>
#include <cstdint>
#include <cstddef>

// MHA: B=2, S=2048, D=1024, H=16, DK=DV=64, causal, scale=1/8 on scores.
// Pipeline: wtrans (W->bf16 W^T) ; cvt (Q/K/V fp32->bf16) ; projection GEMMs
// (m97-style global_load_lds, V written transposed per head) ; causal flash
// attention (swapped ops, LDS P-bounce, dbuf) ; output GEMM -> fp32.

typedef __bf16 bf16x8 __attribute__((ext_vector_type(8)));
typedef __bf16 bf16x4 __attribute__((ext_vector_type(4)));
typedef float f32x4 __attribute__((ext_vector_type(4)));
typedef unsigned int u32x4 __attribute__((ext_vector_type(4)));

#define MFMA __builtin_amdgcn_mfma_f32_16x16x32_bf16

static __device__ __forceinline__ __bf16 f2b(float f) { return (__bf16)f; }

static __device__ __forceinline__ void gload_lds16(const void* g, void* l) {
  __builtin_amdgcn_global_load_lds(
      (const __attribute__((address_space(1))) void*)g,
      (__attribute__((address_space(3))) void*)l, 16, 0, 0);
}

// ---------------------------------------------------------------------------
// Weight transpose+convert: O[n][k] = (bf16) W[k][n], each 1024x1024.
// ---------------------------------------------------------------------------
__global__ __launch_bounds__(256) void wtrans_kernel(
    const float* __restrict__ w0, const float* __restrict__ w1,
    const float* __restrict__ w2, const float* __restrict__ w3,
    __bf16* __restrict__ outT)
{
  const int z = blockIdx.z;
  const float* W = (z == 0) ? w0 : (z == 1) ? w1 : (z == 2) ? w2 : w3;
  __bf16* O = outT + (size_t)z * 1048576;
  __shared__ float t[32][33];
  const int tx = threadIdx.x & 31, ty = threadIdx.x >> 5;
  const int kb = blockIdx.y * 32, nb = blockIdx.x * 32;
#pragma unroll
  for (int i = 0; i < 4; i++)
    t[ty + i * 8][tx] = W[(size_t)(kb + ty + i * 8) * 1024 + nb + tx];
  __syncthreads();
#pragma unroll
  for (int i = 0; i < 4; i++)
    O[(size_t)(nb + ty + i * 8) * 1024 + kb + tx] = f2b(t[tx][ty + i * 8]);
}

// ---------------------------------------------------------------------------
// Q/K/V fp32 -> bf16 copy (same [4096][1024] layout). grid (512,3).
// ---------------------------------------------------------------------------
__global__ __launch_bounds__(256) void cvt_kernel(
    const float* __restrict__ a0, const float* __restrict__ a1,
    const float* __restrict__ a2, __bf16* __restrict__ o0,
    __bf16* __restrict__ o1, __bf16* __restrict__ o2)
{
  const int z = blockIdx.y;
  const float* src = (z == 0) ? a0 : (z == 1) ? a1 : a2;
  __bf16* dst = (z == 0) ? o0 : (z == 1) ? o1 : o2;
  const int idx = blockIdx.x * 256 + threadIdx.x;
#pragma unroll
  for (int it = 0; it < 4; ++it) {
    const size_t c = (size_t)(idx + it * 131072) * 8;
    f32x4 v0 = *(const f32x4*)&src[c];
    f32x4 v1 = *(const f32x4*)&src[c + 4];
    bf16x8 w = {f2b(v0[0]), f2b(v0[1]), f2b(v0[2]), f2b(v0[3]),
                f2b(v1[0]), f2b(v1[1]), f2b(v1[2]), f2b(v1[3])};
    *(bf16x8*)&dst[c] = w;
  }
}

// ---------------------------------------------------------------------------
// FAST projection GEMM (m97 structure): C = A(bf16 [4096,1024]) * W^T(bf16).
// global_load_lds width-16 for both operands, linear LDS [128][32], BK=32.
// XCD-bijective block remap. z=0/1 -> head-major scatter; z=2 -> V^T.
// ---------------------------------------------------------------------------
__global__ __launch_bounds__(256) void gemm_proj_bf16_kernel(
    const __bf16* __restrict__ A0, const __bf16* __restrict__ A1,
    const __bf16* __restrict__ A2, const __bf16* __restrict__ WT,
    __bf16* __restrict__ C0, __bf16* __restrict__ C1, __bf16* __restrict__ C2)
{
  const int z = blockIdx.y;
  const __bf16* A = (z == 0) ? A0 : (z == 1) ? A1 : A2;
  const __bf16* W = WT + (size_t)z * 1048576;
  __bf16* C = (z == 0) ? C0 : (z == 1) ? C1 : C2;

  const int bid = blockIdx.x;
  const int t = (bid & 7) * 32 + (bid >> 3);   // XCD-contiguous (256%8==0)
  const int mt = t >> 3, nt = t & 7;
  const int mbase = mt * 128, nbase = nt * 128;

  __shared__ __align__(16) __bf16 As[128][32];
  __shared__ __align__(16) __bf16 Bs[128][32];

  const int tid = threadIdx.x;
  const int wid = tid >> 6, lane = tid & 63;
  const int wr = wid >> 1, wc = wid & 1;
  const int lr = lane & 15, kg = lane >> 4;

  f32x4 acc[4][4] = {};

  const int srow = tid >> 2, scol = (tid & 3) * 8;  // chunk -> (row, col8)
  const int wbase = tid & 192;                       // wave-uniform chunk base

  for (int kb = 0; kb < 32; ++kb) {
    const int k0 = kb * 32;
    __syncthreads();  // all waves done with previous tile's LDS
#pragma unroll
    for (int p = 0; p < 2; ++p) {
      const int r = srow + p * 64;
      gload_lds16(&A[(size_t)(mbase + r) * 1024 + k0 + scol],
                  (__bf16*)As + (size_t)(p * 256 + wbase) * 8);
      gload_lds16(&W[(size_t)(nbase + r) * 1024 + k0 + scol],
                  (__bf16*)Bs + (size_t)(p * 256 + wbase) * 8);
    }
    __syncthreads();  // drains vmcnt(0): tiles resident

    bf16x8 af[4], bfr[4];
#pragma unroll
    for (int i = 0; i < 4; i++) af[i] = *(const bf16x8*)&As[wr * 64 + i * 16 + lr][kg * 8];
#pragma unroll
    for (int j = 0; j < 4; j++) bfr[j] = *(const bf16x8*)&Bs[wc * 64 + j * 16 + lr][kg * 8];
#pragma unroll
    for (int i = 0; i < 4; i++)
#pragma unroll
      for (int j = 0; j < 4; j++)
        acc[i][j] = MFMA(af[i], bfr[j], acc[i][j], 0, 0, 0);
  }

  if (z == 2) {
#pragma unroll
    for (int i = 0; i < 4; i++)
#pragma unroll
      for (int j = 0; j < 4; j++) {
        const int m0 = mbase + wr * 64 + i * 16 + kg * 4;
        const int n = nbase + wc * 64 + j * 16 + lr;
        const int b = m0 >> 11, s = m0 & 2047, h = n >> 6, dv = n & 63;
        bf16x4 w;
#pragma unroll
        for (int r = 0; r < 4; r++) w[r] = f2b(acc[i][j][r]);
        *(bf16x4*)&C[(((size_t)(b * 16 + h)) * 64 + dv) * 2048 + s] = w;
      }
  } else {
#pragma unroll
    for (int i = 0; i < 4; i++)
#pragma unroll
      for (int j = 0; j < 4; j++)
#pragma unroll
        for (int r = 0; r < 4; r++) {
          const int m = mbase + wr * 64 + i * 16 + kg * 4 + r;
          const int n = nbase + wc * 64 + j * 16 + lr;
          const int b = m >> 11, s = m & 2047, h = n >> 6, dk = n & 63;
          C[(((size_t)(b * 16 + h)) * 2048 + s) * 64 + dk] = f2b(acc[i][j][r]);
        }
  }
}

// ---------------------------------------------------------------------------
// FALLBACK projection GEMM (round-5 verified, fp32 A) — used if ws too small.
// ---------------------------------------------------------------------------
__global__ __launch_bounds__(256) void gemm_proj_f32_kernel(
    const float* __restrict__ A0, const float* __restrict__ A1,
    const float* __restrict__ A2, const __bf16* __restrict__ WT,
    __bf16* __restrict__ C0, __bf16* __restrict__ C1, __bf16* __restrict__ C2)
{
  const int z = blockIdx.y;
  const float* A = (z == 0) ? A0 : (z == 1) ? A1 : A2;
  const __bf16* W = WT + (size_t)z * 1048576;
  __bf16* C = (z == 0) ? C0 : (z == 1) ? C1 : C2;

  const int mt = blockIdx.x >> 3, nt = blockIdx.x & 7;
  const int mbase = mt * 128, nbase = nt * 128;

  __shared__ __align__(16) __bf16 As[128][40];
  __shared__ __align__(16) __bf16 Bs[128][40];

  const int tid = threadIdx.x;
  const int wid = tid >> 6, lane = tid & 63;
  const int wr = wid >> 1, wc = wid & 1;
  const int lr = lane & 15, kg = lane >> 4;

  f32x4 acc[4][4] = {};
  const int arow = tid >> 3, ac0 = (tid & 7) * 4;

  for (int kb = 0; kb < 32; ++kb) {
    const int k0 = kb * 32;
#pragma unroll
    for (int p = 0; p < 4; ++p) {
      const int r = arow + p * 32;
      f32x4 av = *(const f32x4*)&A[(size_t)(mbase + r) * 1024 + k0 + ac0];
      bf16x4 cv = {f2b(av[0]), f2b(av[1]), f2b(av[2]), f2b(av[3])};
      *(bf16x4*)&As[r][ac0] = cv;
    }
#pragma unroll
    for (int p = 0; p < 2; ++p) {
      const int idx = p * 256 + tid;
      const int r = idx >> 2, c8 = (idx & 3) * 8;
      *(u32x4*)&Bs[r][c8] = *(const u32x4*)&W[(size_t)(nbase + r) * 1024 + k0 + c8];
    }
    __syncthreads();

    bf16x8 af[4], bfr[4];
#pragma unroll
    for (int i = 0; i < 4; i++) af[i] = *(const bf16x8*)&As[wr * 64 + i * 16 + lr][kg * 8];
#pragma unroll
    for (int j = 0; j < 4; j++) bfr[j] = *(const bf16x8*)&Bs[wc * 64 + j * 16 + lr][kg * 8];
#pragma unroll
    for (int i = 0; i < 4; i++)
#pragma unroll
      for (int j = 0; j < 4; j++)
        acc[i][j] = MFMA(af[i], bfr[j], acc[i][j], 0, 0, 0);
    __syncthreads();
  }

  if (z == 2) {
#pragma unroll
    for (int i = 0; i < 4; i++)
#pragma unroll
      for (int j = 0; j < 4; j++) {
        const int m0 = mbase + wr * 64 + i * 16 + kg * 4;
        const int n = nbase + wc * 64 + j * 16 + lr;
        const int b = m0 >> 11, s = m0 & 2047, h = n >> 6, dv = n & 63;
        bf16x4 w;
#pragma unroll
        for (int r = 0; r < 4; r++) w[r] = f2b(acc[i][j][r]);
        *(bf16x4*)&C[(((size_t)(b * 16 + h)) * 64 + dv) * 2048 + s] = w;
      }
  } else {
#pragma unroll
    for (int i = 0; i < 4; i++)
#pragma unroll
      for (int j = 0; j < 4; j++)
#pragma unroll
        for (int r = 0; r < 4; r++) {
          const int m = mbase + wr * 64 + i * 16 + kg * 4 + r;
          const int n = nbase + wc * 64 + j * 16 + lr;
          const int b = m >> 11, s = m & 2047, h = n >> 6, dk = n & 63;
          C[(((size_t)(b * 16 + h)) * 2048 + s) * 64 + dk] = f2b(acc[i][j][r]);
        }
  }
}

// ---------------------------------------------------------------------------
// Causal flash attention v4 (unchanged, verified round 5).
// ---------------------------------------------------------------------------
__global__ __launch_bounds__(256) void attn_kernel(
    const __bf16* __restrict__ Qh, const __bf16* __restrict__ Kh,
    const __bf16* __restrict__ VTh, __bf16* __restrict__ AO)
{
  const int lin = blockIdx.y * 16 + blockIdx.x;
  const int l = (lin & 7) * 64 + (lin >> 3);
  const int xp = l & 15, bh = l >> 4;
  const int b = bh >> 4, h = bh & 15;
  const __bf16* Qp = Qh + (size_t)bh * 2048 * 64;
  const __bf16* Kp = Kh + (size_t)bh * 2048 * 64;
  const __bf16* Vp = VTh + (size_t)bh * 64 * 2048;

  __shared__ __align__(16) __bf16 Ks[2][64][72];
  __shared__ __align__(16) __bf16 Vt[2][64][72];
  __shared__ __align__(16) __bf16 Ps[4][16][72];

  const int tid = threadIdx.x, wid = tid >> 6, lane = tid & 63;
  const int lr = lane & 15, kg = lane >> 4;
  const int sr0 = tid >> 3, sc0 = (tid & 7) * 8;
  const float SCALE = 0.125f * 1.44269504f;

#pragma unroll
  for (int phase = 0; phase < 2; ++phase) {
    const int qblk = phase ? (31 - xp) : xp;
    const int qbase = qblk << 6;
    const int nkv = qblk + 1;
    const int wq = qbase + wid * 16;

    bf16x8 qf0 = *(const bf16x8*)&Qp[(size_t)(wq + lr) * 64 + kg * 8];
    bf16x8 qf1 = *(const bf16x8*)&Qp[(size_t)(wq + lr) * 64 + 32 + kg * 8];

    f32x4 ot[4] = {};
    float mrow = -1e30f, lsum = 0.f;

    u32x4 kr0 = *(const u32x4*)&Kp[(size_t)sr0 * 64 + sc0];
    u32x4 kr1 = *(const u32x4*)&Kp[(size_t)(sr0 + 32) * 64 + sc0];
    u32x4 vr0 = *(const u32x4*)&Vp[(size_t)sr0 * 2048 + sc0];
    u32x4 vr1 = *(const u32x4*)&Vp[(size_t)(sr0 + 32) * 2048 + sc0];
    __syncthreads();
    *(u32x4*)&Ks[0][sr0][sc0] = kr0;
    *(u32x4*)&Ks[0][sr0 + 32][sc0] = kr1;
    *(u32x4*)&Vt[0][sr0][sc0] = vr0;
    *(u32x4*)&Vt[0][sr0 + 32][sc0] = vr1;

    int cur = 0;
    for (int t = 0; t < nkv; ++t) {
      const int kv0 = t << 6;
      const bool pre = (t + 1 < nkv);
      if (pre) {
        const int nkv0 = kv0 + 64;
        kr0 = *(const u32x4*)&Kp[(size_t)(nkv0 + sr0) * 64 + sc0];
        kr1 = *(const u32x4*)&Kp[(size_t)(nkv0 + sr0 + 32) * 64 + sc0];
        vr0 = *(const u32x4*)&Vp[(size_t)sr0 * 2048 + nkv0 + sc0];
        vr1 = *(const u32x4*)&Vp[(size_t)(sr0 + 32) * 2048 + nkv0 + sc0];
      }
      __syncthreads();

      if (kv0 <= wq + 15) {
        f32x4 st[4] = {};
        __builtin_amdgcn_s_setprio(1);
#pragma unroll
        for (int kvt = 0; kvt < 4; ++kvt) {
          bf16x8 kf0 = *(const bf16x8*)&Ks[cur][kvt * 16 + lr][kg * 8];
          bf16x8 kf1 = *(const bf16x8*)&Ks[cur][kvt * 16 + lr][32 + kg * 8];
          st[kvt] = MFMA(kf0, qf0, st[kvt], 0, 0, 0);
          st[kvt] = MFMA(kf1, qf1, st[kvt], 0, 0, 0);
        }
        __builtin_amdgcn_s_setprio(0);

        const int qidx = wq + lr;
        const bool needmask = (kv0 + 63) > wq;
        float sv[16];
        float mx = -1e30f;
#pragma unroll
        for (int kvt = 0; kvt < 4; ++kvt)
#pragma unroll
          for (int r = 0; r < 4; ++r) {
            float v = st[kvt][r] * SCALE;
            if (needmask && (kv0 + kvt * 16 + kg * 4 + r > qidx)) v = -1e30f;
            sv[kvt * 4 + r] = v;
            mx = fmaxf(mx, v);
          }
        mx = fmaxf(mx, __shfl_xor(mx, 16));
        mx = fmaxf(mx, __shfl_xor(mx, 32));
        const float mnew = fmaxf(mrow, mx);
        const float scl = exp2f(mrow - mnew);
        mrow = mnew;
        float rs = 0.f;
#pragma unroll
        for (int kvt = 0; kvt < 4; ++kvt) {
          bf16x4 pk;
#pragma unroll
          for (int r = 0; r < 4; ++r) {
            const float p = exp2f(sv[kvt * 4 + r] - mnew);
            rs += p;
            pk[r] = f2b(p);
          }
          *(bf16x4*)&Ps[wid][lr][kvt * 16 + kg * 4] = pk;
        }
        rs += __shfl_xor(rs, 16);
        rs += __shfl_xor(rs, 32);
        lsum = lsum * scl + rs;
#pragma unroll
        for (int dvt = 0; dvt < 4; ++dvt) ot[dvt] *= scl;

#pragma unroll
        for (int h2 = 0; h2 < 2; ++h2) {
          bf16x8 pf = *(const bf16x8*)&Ps[wid][lr][h2 * 32 + kg * 8];
          __builtin_amdgcn_s_setprio(1);
#pragma unroll
          for (int dvt = 0; dvt < 4; ++dvt) {
            bf16x8 vf = *(const bf16x8*)&Vt[cur][dvt * 16 + lr][h2 * 32 + kg * 8];
            ot[dvt] = MFMA(vf, pf, ot[dvt], 0, 0, 0);
          }
          __builtin_amdgcn_s_setprio(0);
        }
      }

      if (pre) {
        const int nb = cur ^ 1;
        *(u32x4*)&Ks[nb][sr0][sc0] = kr0;
        *(u32x4*)&Ks[nb][sr0 + 32][sc0] = kr1;
        *(u32x4*)&Vt[nb][sr0][sc0] = vr0;
        *(u32x4*)&Vt[nb][sr0 + 32][sc0] = vr1;
      }
      cur ^= 1;
    }

    const float rl = 1.f / lsum;
    const int q = wq + lr;
#pragma unroll
    for (int dvt = 0; dvt < 4; ++dvt) {
      bf16x4 w;
#pragma unroll
      for (int r = 0; r < 4; ++r) w[r] = f2b(ot[dvt][r] * rl);
      *(bf16x4*)&AO[((size_t)(b * 2048 + q)) * 1024 + h * 64 + dvt * 16 + kg * 4] = w;
    }
  }
}

// ---------------------------------------------------------------------------
// Output GEMM (m97 structure): out(fp32) = AO(bf16) * Wo^T(bf16).
// ---------------------------------------------------------------------------
__global__ __launch_bounds__(256) void gemm_out_kernel(
    const __bf16* __restrict__ A, const __bf16* __restrict__ WT,
    float* __restrict__ Out)
{
  const int bid = blockIdx.x;
  const int t = (bid & 7) * 32 + (bid >> 3);
  const int mt = t >> 3, nt = t & 7;
  const int mbase = mt * 128, nbase = nt * 128;

  __shared__ __align__(16) __bf16 As[128][32];
  __shared__ __align__(16) __bf16 Bs[128][32];

  const int tid = threadIdx.x;
  const int wid = tid >> 6, lane = tid & 63;
  const int wr = wid >> 1, wc = wid & 1;
  const int lr = lane & 15, kg = lane >> 4;

  f32x4 acc[4][4] = {};

  const int srow = tid >> 2, scol = (tid & 3) * 8;
  const int wbase = tid & 192;

  for (int kb = 0; kb < 32; ++kb) {
    const int k0 = kb * 32;
    __syncthreads();
#pragma unroll
    for (int p = 0; p < 2; ++p) {
      const int r = srow + p * 64;
      gload_lds16(&A[(size_t)(mbase + r) * 1024 + k0 + scol],
                  (__bf16*)As + (size_t)(p * 256 + wbase) * 8);
      gload_lds16(&WT[(size_t)(nbase + r) * 1024 + k0 + scol],
                  (__bf16*)Bs + (size_t)(p * 256 + wbase) * 8);
    }
    __syncthreads();

    bf16x8 af[4], bfr[4];
#pragma unroll
    for (int i = 0; i < 4; i++) af[i] = *(const bf16x8*)&As[wr * 64 + i * 16 + lr][kg * 8];
#pragma unroll
    for (int j = 0; j < 4; j++) bfr[j] = *(const bf16x8*)&Bs[wc * 64 + j * 16 + lr][kg * 8];
#pragma unroll
    for (int i = 0; i < 4; i++)
#pragma unroll
      for (int j = 0; j < 4; j++)
        acc[i][j] = MFMA(af[i], bfr[j], acc[i][j], 0, 0, 0);
  }

#pragma unroll
  for (int i = 0; i < 4; i++)
#pragma unroll
    for (int j = 0; j < 4; j++)
#pragma unroll
      for (int r = 0; r < 4; r++) {
        const int m = mbase + wr * 64 + i * 16 + kg * 4 + r;
        const int n = nbase + wc * 64 + j * 16 + lr;
        Out[(size_t)m * 1024 + n] = acc[i][j][r];
      }
}

// ---------------------------------------------------------------------------
extern "C" void kernel_launch(void* const* d_in, const int* in_sizes, int n_in,
                              void* d_out, int out_size, void* d_ws, size_t ws_size,
                              hipStream_t stream) {
  const float* Q  = (const float*)d_in[0];
  const float* K  = (const float*)d_in[1];
  const float* V  = (const float*)d_in[2];
  const float* Wq = (const float*)d_in[3];
  const float* Wk = (const float*)d_in[4];
  const float* Wv = (const float*)d_in[5];
  const float* Wo = (const float*)d_in[6];
  float* out = (float*)d_out;

  const size_t M4 = 4194304;  // elems per 4096x1024 bf16 buffer
  __bf16* wT  = (__bf16*)d_ws;          // 4M elems (4 x 1024x1024)
  __bf16* qb  = wT + M4;                // head-major Q
  __bf16* kb  = qb + M4;                // head-major K
  __bf16* vtb = kb + M4;                // per-head V^T

  const bool fast = ws_size >= (size_t)(28 * 1048576) * 2;  // 56 MiB

  wtrans_kernel<<<dim3(32, 32, 4), 256, 0, stream>>>(Wq, Wk, Wv, Wo, wT);

  __bf16* ao;
  if (fast) {
    __bf16* qa = vtb + M4;   // bf16 copies of inputs
    __bf16* ka = qa + M4;
    __bf16* va = ka + M4;
    ao = qa;                 // reuse qa after gemm_proj consumed it
    cvt_kernel<<<dim3(512, 3), 256, 0, stream>>>(Q, K, V, qa, ka, va);
    gemm_proj_bf16_kernel<<<dim3(256, 3), 256, 0, stream>>>(qa, ka, va, wT,
                                                            qb, kb, vtb);
  } else {
    ao = vtb + M4;
    gemm_proj_f32_kernel<<<dim3(256, 3), 256, 0, stream>>>(Q, K, V, wT,
                                                           qb, kb, vtb);
  }

  attn_kernel<<<dim3(16, 32), 256, 0, stream>>>(qb, kb, vtb, ao);
  gemm_out_kernel<<<dim3(256), 256, 0, stream>>>(ao, wT + 3 * 1048576, out);
}